// Round 5
// baseline (210.664 us; speedup 1.0000x reference)
//
#include <hip/hip_runtime.h>
#include <hip/hip_cooperative_groups.h>

namespace cg = cooperative_groups;

// Problem constants (match reference).
constexpr int Hh = 256;
constexpr int Ww = 256;
constexpr int Dd = 256;
constexpr int NB = 2048;

constexpr int CH = 16;   // scan elements per thread (chunk length)
constexpr int NC = 16;   // chunks per scan axis (256/16)
constexpr int D4 = 64;   // D in float4 units (one wave spans full D)

typedef float f4 __attribute__((ext_vector_type(4)));

// ---------------------------------------------------------------------------
// Fused SAT build + pool, one cooperative kernel, 256 blocks x 1024 threads
// (1 block/CU). Phases separated by grid.sync() instead of kernel boundaries.
//   A: row-prefix along W  (block = row h)       R feat 64MiB (NT), W sat 64MiB
//   B: col-prefix along H  (block = column w)    R+W sat in place (L3-resident)
//   C: 4-corner SAT lookup (block = 8 boxes)     R sat ~8MiB, W out 2MiB (NT)
// Bounds math replicates f32 JAX semantics exactly:
//   lo = max(0, floor(lo_f*size));  hi = rint(hi_f*size + 0.5)  (ties-even)
//   hi = min(size, max(lo+1, hi))
// ---------------------------------------------------------------------------
__global__ void __launch_bounds__(1024) roi_fused(const f4* __restrict__ feat,
                                                  const float* __restrict__ boxes,
                                                  f4* __restrict__ sat,
                                                  f4* __restrict__ out) {
    cg::grid_group grid = cg::this_grid();
    const int tid = threadIdx.x;
    const int dl  = tid & (D4 - 1);      // float4 lane over d
    const int ck  = tid >> 6;            // chunk index, wave-uniform

    __shared__ f4 cs[NC][D4];

    // ---- Phase A: row-prefix along W ----
    {
        const int h = blockIdx.x;
        const size_t base = ((size_t)h * Ww + (size_t)ck * CH) * D4 + dl;
        f4 v[CH];
#pragma unroll
        for (int j = 0; j < CH; ++j)
            v[j] = __builtin_nontemporal_load(feat + base + (size_t)j * D4);
#pragma unroll
        for (int j = 1; j < CH; ++j) v[j] += v[j - 1];

        cs[ck][dl] = v[CH - 1];
        __syncthreads();
        f4 off = {0.f, 0.f, 0.f, 0.f};
        for (int k = 0; k < ck; ++k) off += cs[k][dl];   // ck wave-uniform

#pragma unroll
        for (int j = 0; j < CH; ++j) sat[base + (size_t)j * D4] = v[j] + off;
    }

    grid.sync();

    // ---- Phase B: col-prefix along H, in place ----
    {
        const int w = blockIdx.x;
        f4* p = sat + ((size_t)ck * CH * Ww + w) * D4 + dl;
        const size_t stride = (size_t)Ww * D4;

        f4 v[CH];
#pragma unroll
        for (int j = 0; j < CH; ++j) v[j] = p[(size_t)j * stride];
#pragma unroll
        for (int j = 1; j < CH; ++j) v[j] += v[j - 1];

        cs[ck][dl] = v[CH - 1];
        __syncthreads();
        f4 off = {0.f, 0.f, 0.f, 0.f};
        for (int k = 0; k < ck; ++k) off += cs[k][dl];

#pragma unroll
        for (int j = 0; j < CH; ++j) p[(size_t)j * stride] = v[j] + off;
    }

    grid.sync();

    // ---- Phase C: pool. Waves 0..7 each own one box (lanes span d). ----
    if (ck < 8) {
        const int n = blockIdx.x * 8 + ck;

        float x1 = boxes[n * 4 + 0];
        float y1 = boxes[n * 4 + 1];
        float x2 = boxes[n * 4 + 2];
        float y2 = boxes[n * 4 + 3];

        int cl = max(0, (int)floorf(x1 * 256.0f));
        int chi = (int)rintf(x2 * 256.0f + 0.5f);
        chi = min(Ww, max(cl + 1, chi));

        int rl = max(0, (int)floorf(y1 * 256.0f));
        int rh = (int)rintf(y2 * 256.0f + 0.5f);
        rh = min(Hh, max(rl + 1, rh));

        f4 s = sat[(((size_t)(rh - 1) * Ww) + (chi - 1)) * D4 + dl];
        if (cl > 0) s -= sat[(((size_t)(rh - 1) * Ww) + (cl - 1)) * D4 + dl];
        if (rl > 0) {
            s -= sat[(((size_t)(rl - 1) * Ww) + (chi - 1)) * D4 + dl];
            if (cl > 0) s += sat[(((size_t)(rl - 1) * Ww) + (cl - 1)) * D4 + dl];
        }

        float count = (float)((rh - rl) * (chi - cl));
        f4 r = s / count;
        __builtin_nontemporal_store(r, out + (size_t)n * D4 + dl);
    }
}

// ---------------------------------------------------------------------------
// Fallback (cooperative launch failure or tiny ws): direct summation.
// ---------------------------------------------------------------------------
__global__ void __launch_bounds__(256) roi_pool_naive(const float* __restrict__ feat,
                                                      const float* __restrict__ boxes,
                                                      float* __restrict__ out) {
    int n = blockIdx.x;
    int d = threadIdx.x;

    float x1 = boxes[n * 4 + 0];
    float y1 = boxes[n * 4 + 1];
    float x2 = boxes[n * 4 + 2];
    float y2 = boxes[n * 4 + 3];

    int cl = max(0, (int)floorf(x1 * 256.0f));
    int ch = (int)rintf(x2 * 256.0f + 0.5f);
    ch = min(Ww, max(cl + 1, ch));
    int rl = max(0, (int)floorf(y1 * 256.0f));
    int rh = (int)rintf(y2 * 256.0f + 0.5f);
    rh = min(Hh, max(rl + 1, rh));

    float s = 0.0f;
    for (int r = rl; r < rh; ++r) {
        const float* row = feat + ((size_t)r * Ww) * Dd + d;
        for (int c = cl; c < ch; ++c) s += row[(size_t)c * Dd];
    }
    float count = (float)((rh - rl) * (ch - cl));
    out[(size_t)n * Dd + d] = s / count;
}

extern "C" void kernel_launch(void* const* d_in, const int* in_sizes, int n_in,
                              void* d_out, int out_size, void* d_ws, size_t ws_size,
                              hipStream_t stream) {
    const float* feat  = (const float*)d_in[0];   // (256,256,256) f32
    const float* boxes = (const float*)d_in[1];   // (2048,4) f32

    const size_t sat_bytes = (size_t)Hh * Ww * Dd * sizeof(float);  // 64 MiB

    if (ws_size >= sat_bytes) {
        const f4* featv = (const f4*)feat;
        f4* sat  = (f4*)d_ws;
        f4* outv = (f4*)d_out;
        void* args[] = {(void*)&featv, (void*)&boxes, (void*)&sat, (void*)&outv};
        hipError_t e = hipLaunchCooperativeKernel((const void*)roi_fused,
                                                  dim3(Hh), dim3(1024),
                                                  args, 0, stream);
        if (e == hipSuccess) return;
        // fall through to naive path if cooperative launch is unavailable
    }
    roi_pool_naive<<<NB, 256, 0, stream>>>(feat, boxes, (float*)d_out);
}

// Round 6
// 189.742 us; speedup vs baseline: 1.1103x; 1.1103x over previous
//
#include <hip/hip_runtime.h>

// Problem constants (match reference).
constexpr int Hh = 256;
constexpr int Ww = 256;
constexpr int Dd = 256;
constexpr int NB = 2048;

typedef float f4 __attribute__((ext_vector_type(4)));

// ---------------------------------------------------------------------------
// K1: row-prefix along w. Block = one row h (1024 thr = 16 w-chunks x 64
// d-lanes, 16 scan elems/thread in registers, chunk totals via LDS).
// Reads feat contiguously; writes the prefix TRANSPOSED:
//   P_T[w][half][h][f]   (f = d/4 within half, 32 f4 = 128 channels)
// so K2 can read each column contiguously. Stores are 2x512B per instr,
// strided — fire-and-forget, latency-tolerant.
// ---------------------------------------------------------------------------
__global__ void __launch_bounds__(1024) k1_rowscan(const f4* __restrict__ feat,
                                                   f4* __restrict__ pt) {
    const int tid  = threadIdx.x;
    const int dl   = tid & 63;           // f4 lane over d (all 256 ch)
    const int ck   = tid >> 6;           // w-chunk, wave-uniform
    const int h    = blockIdx.x;
    const int half = dl >> 5;
    const int f    = dl & 31;

    __shared__ f4 cs[16][64];

    const size_t rbase = ((size_t)h * Ww + ck * 16) * 64 + dl;
    f4 v[16];
#pragma unroll
    for (int j = 0; j < 16; ++j)
        v[j] = __builtin_nontemporal_load(feat + rbase + (size_t)j * 64);
#pragma unroll
    for (int j = 1; j < 16; ++j) v[j] += v[j - 1];

    cs[ck][dl] = v[15];
    __syncthreads();
    f4 off = {0.f, 0.f, 0.f, 0.f};
    for (int k = 0; k < ck; ++k) off += cs[k][dl];   // ck wave-uniform

#pragma unroll
    for (int j = 0; j < 16; ++j) {
        int w = ck * 16 + j;
        pt[(((size_t)w * 2 + half) * Hh + h) * 32 + f] = v[j] + off;
    }
}

// ---------------------------------------------------------------------------
// K2: per (column w, d-half): contiguous 128 KiB read of P_T column,
// column-prefix over h (32 h-chunks x 8 elems, LDS chunk totals), stage the
// SAT column C in LDS [256][32 f4] = 128 KiB, then serve all boxes whose
// cl-1 or ch-1 equals w:  out[n] += sign * (C[rh-1]-C[rl-1]) / count.
// Exactly <=2 commutative atomic adds per out element -> deterministic.
// Bounds math replicates f32 JAX semantics exactly:
//   lo = max(0, floor(lo_f*size));  hi = rint(hi_f*size + 0.5)  (ties-even)
//   hi = min(size, max(lo+1, hi))
// ---------------------------------------------------------------------------
__global__ void __launch_bounds__(1024) k2_colscan_pool(const f4* __restrict__ pt,
                                                        const float* __restrict__ boxes,
                                                        float* __restrict__ out) {
    extern __shared__ f4 lds[];          // cs: 32*32 f4, Cbuf: 256*32 f4
    f4* cs   = lds;                      // [32][32]
    f4* Cbuf = lds + 32 * 32;            // [256][32]

    const int tid  = threadIdx.x;
    const int dl   = tid & 31;           // f4 lane within half (32 f4 = 128 ch)
    const int hc   = tid >> 5;           // h-chunk (32 chunks of 8)
    const int w    = blockIdx.x >> 1;
    const int half = blockIdx.x & 1;

    const size_t base = (((size_t)w * 2 + half) * Hh + hc * 8) * 32 + dl;
    f4 v[8];
#pragma unroll
    for (int j = 0; j < 8; ++j) v[j] = pt[base + (size_t)j * 32];
#pragma unroll
    for (int j = 1; j < 8; ++j) v[j] += v[j - 1];

    cs[hc * 32 + dl] = v[7];
    __syncthreads();
    f4 off = {0.f, 0.f, 0.f, 0.f};
    for (int k = 0; k < hc; ++k) off += cs[k * 32 + dl];

#pragma unroll
    for (int j = 0; j < 8; ++j) Cbuf[(hc * 8 + j) * 32 + dl] = v[j] + off;
    __syncthreads();

    // Serve boxes referencing this column (avg ~16 matches per column).
    for (int n = tid; n < NB; n += 1024) {
        float x1 = boxes[n * 4 + 0];
        float y1 = boxes[n * 4 + 1];
        float x2 = boxes[n * 4 + 2];
        float y2 = boxes[n * 4 + 3];

        int cl = max(0, (int)floorf(x1 * 256.0f));
        int ch = (int)rintf(x2 * 256.0f + 0.5f);
        ch = min(Ww, max(cl + 1, ch));
        int rl = max(0, (int)floorf(y1 * 256.0f));
        int rh = (int)rintf(y2 * 256.0f + 0.5f);
        rh = min(Hh, max(rl + 1, rh));

        float sgn;
        if (ch - 1 == w)      sgn =  1.0f;
        else if (cl - 1 == w) sgn = -1.0f;
        else continue;

        float scale = sgn / (float)((rh - rl) * (ch - cl));
        float* o = out + (size_t)n * Dd + half * 128;
        for (int fi = 0; fi < 32; ++fi) {
            f4 c = Cbuf[(rh - 1) * 32 + fi];
            if (rl > 0) {
                f4 clo = Cbuf[(rl - 1) * 32 + fi];
                c -= clo;
            }
            c *= scale;
            atomicAdd(o + fi * 4 + 0, c.x);
            atomicAdd(o + fi * 4 + 1, c.y);
            atomicAdd(o + fi * 4 + 2, c.z);
            atomicAdd(o + fi * 4 + 3, c.w);
        }
    }
}

// ---------------------------------------------------------------------------
// Fallback (ws too small): direct summation.
// ---------------------------------------------------------------------------
__global__ void __launch_bounds__(256) roi_pool_naive(const float* __restrict__ feat,
                                                      const float* __restrict__ boxes,
                                                      float* __restrict__ out) {
    int n = blockIdx.x;
    int d = threadIdx.x;

    float x1 = boxes[n * 4 + 0];
    float y1 = boxes[n * 4 + 1];
    float x2 = boxes[n * 4 + 2];
    float y2 = boxes[n * 4 + 3];

    int cl = max(0, (int)floorf(x1 * 256.0f));
    int ch = (int)rintf(x2 * 256.0f + 0.5f);
    ch = min(Ww, max(cl + 1, ch));
    int rl = max(0, (int)floorf(y1 * 256.0f));
    int rh = (int)rintf(y2 * 256.0f + 0.5f);
    rh = min(Hh, max(rl + 1, rh));

    float s = 0.0f;
    for (int r = rl; r < rh; ++r) {
        const float* row = feat + ((size_t)r * Ww) * Dd + d;
        for (int c = cl; c < ch; ++c) s += row[(size_t)c * Dd];
    }
    float count = (float)((rh - rl) * (ch - cl));
    out[(size_t)n * Dd + d] = s / count;
}

extern "C" void kernel_launch(void* const* d_in, const int* in_sizes, int n_in,
                              void* d_out, int out_size, void* d_ws, size_t ws_size,
                              hipStream_t stream) {
    const float* feat  = (const float*)d_in[0];   // (256,256,256) f32
    const float* boxes = (const float*)d_in[1];   // (2048,4) f32

    const size_t pt_bytes  = (size_t)Hh * Ww * Dd * sizeof(float);  // 64 MiB
    const size_t lds_bytes = (32 * 32 + 256 * 32) * sizeof(f4);     // 147456 B

    if (ws_size >= pt_bytes) {
        f4* pt = (f4*)d_ws;
        // out receives only atomic adds -> must start at zero every call.
        hipMemsetAsync(d_out, 0, (size_t)NB * Dd * sizeof(float), stream);
        k1_rowscan<<<Hh, 1024, 0, stream>>>((const f4*)feat, pt);
        hipFuncSetAttribute((const void*)k2_colscan_pool,
                            hipFuncAttributeMaxDynamicSharedMemorySize,
                            (int)lds_bytes);
        k2_colscan_pool<<<Ww * 2, 1024, lds_bytes, stream>>>(pt, boxes, (float*)d_out);
    } else {
        roi_pool_naive<<<NB, 256, 0, stream>>>(feat, boxes, (float*)d_out);
    }
}

// Round 7
// 157.178 us; speedup vs baseline: 1.3403x; 1.2072x over previous
//
#include <hip/hip_runtime.h>

// Problem constants (match reference).
constexpr int Hh = 256;
constexpr int Ww = 256;
constexpr int Dd = 256;
constexpr int NB = 2048;

typedef float f4 __attribute__((ext_vector_type(4)));

// ---------------------------------------------------------------------------
// K1: row-prefix along w:  P[h][w][d] = sum_{w'<=w} feat[h][w'][d].
// Grid = 256 rows x 4 d-quarters = 1024 blocks of 256 thr (~6 blocks/CU so
// load/store phases of different blocks overlap -> R+W streams mix).
// Block: 16 w-chunks x 16 f4-lanes (64 ch quarter). 16 scan elems/thread in
// registers; chunk totals scanned via LDS. All global accesses contiguous
// (lane-major f4), read-once feat via nontemporal loads.
// ---------------------------------------------------------------------------
__global__ void __launch_bounds__(256) k1_rowscan(const f4* __restrict__ feat,
                                                  f4* __restrict__ P) {
    const int tid = threadIdx.x;
    const int dl  = tid & 15;            // f4 lane within quarter (16 f4 = 64 ch)
    const int ck  = tid >> 4;            // w-chunk in [0,16)
    const int h   = blockIdx.x >> 2;
    const int q   = blockIdx.x & 3;      // d-quarter

    __shared__ f4 cs[16][16];

    const size_t base = ((size_t)h * Ww + ck * 16) * 64 + q * 16 + dl;
    f4 v[16];
#pragma unroll
    for (int j = 0; j < 16; ++j)
        v[j] = __builtin_nontemporal_load(feat + base + (size_t)j * 64);
#pragma unroll
    for (int j = 1; j < 16; ++j) v[j] += v[j - 1];

    cs[ck][dl] = v[15];
    __syncthreads();
    f4 off = {0.f, 0.f, 0.f, 0.f};
    for (int k = 0; k < ck; ++k) off += cs[k][dl];   // ck wave-uniform

#pragma unroll
    for (int j = 0; j < 16; ++j) P[base + (size_t)j * 64] = v[j] + off;
}

// ---------------------------------------------------------------------------
// K2: one block per box. out[n][:] = sum_{h in [rl,rh)} (P[h][ch-1][:] -
// P[h][cl-1][:]) / count.  256 thr = 4 row-subsets x 64 f4-lanes; wave reads
// are contiguous 1 KiB; ~350 MB total gather, all L3-resident (P = 64 MiB).
// No atomics; LDS reduce over the 4 row-subsets.
// Bounds math replicates f32 JAX semantics exactly:
//   lo = max(0, floor(lo_f*size));  hi = rint(hi_f*size + 0.5)  (ties-even)
//   hi = min(size, max(lo+1, hi))
// ---------------------------------------------------------------------------
__global__ void __launch_bounds__(256) k2_boxsum(const f4* __restrict__ P,
                                                 const float* __restrict__ boxes,
                                                 f4* __restrict__ out) {
    const int n    = blockIdx.x;
    const int tid  = threadIdx.x;
    const int dl   = tid & 63;           // f4 lane over d (64 f4 = 256 ch)
    const int rsub = tid >> 6;           // row subset in [0,4)

    float x1 = boxes[n * 4 + 0];
    float y1 = boxes[n * 4 + 1];
    float x2 = boxes[n * 4 + 2];
    float y2 = boxes[n * 4 + 3];

    int cl = max(0, (int)floorf(x1 * 256.0f));
    int ch = (int)rintf(x2 * 256.0f + 0.5f);
    ch = min(Ww, max(cl + 1, ch));
    int rl = max(0, (int)floorf(y1 * 256.0f));
    int rh = (int)rintf(y2 * 256.0f + 0.5f);
    rh = min(Hh, max(rl + 1, rh));

    const int colH = ch - 1;             // >= 0 always
    const int colL = cl - 1;             // may be -1 (-> no subtraction)

    f4 acc = {0.f, 0.f, 0.f, 0.f};
    if (colL >= 0) {                     // block-uniform branch
#pragma unroll 2
        for (int h = rl + rsub; h < rh; h += 4) {
            f4 a = P[((size_t)h * Ww + colH) * 64 + dl];
            f4 b = P[((size_t)h * Ww + colL) * 64 + dl];
            acc += a - b;
        }
    } else {
#pragma unroll 2
        for (int h = rl + rsub; h < rh; h += 4) {
            acc += P[((size_t)h * Ww + colH) * 64 + dl];
        }
    }

    __shared__ f4 red[4][64];
    red[rsub][dl] = acc;
    __syncthreads();

    if (rsub == 0) {
        f4 s = red[0][dl] + red[1][dl] + red[2][dl] + red[3][dl];
        float count = (float)((rh - rl) * (ch - cl));
        out[(size_t)n * 64 + dl] = s / count;
    }
}

// ---------------------------------------------------------------------------
// Fallback (ws too small for the 64 MiB prefix buffer): direct summation.
// ---------------------------------------------------------------------------
__global__ void __launch_bounds__(256) roi_pool_naive(const float* __restrict__ feat,
                                                      const float* __restrict__ boxes,
                                                      float* __restrict__ out) {
    int n = blockIdx.x;
    int d = threadIdx.x;

    float x1 = boxes[n * 4 + 0];
    float y1 = boxes[n * 4 + 1];
    float x2 = boxes[n * 4 + 2];
    float y2 = boxes[n * 4 + 3];

    int cl = max(0, (int)floorf(x1 * 256.0f));
    int ch = (int)rintf(x2 * 256.0f + 0.5f);
    ch = min(Ww, max(cl + 1, ch));
    int rl = max(0, (int)floorf(y1 * 256.0f));
    int rh = (int)rintf(y2 * 256.0f + 0.5f);
    rh = min(Hh, max(rl + 1, rh));

    float s = 0.0f;
    for (int r = rl; r < rh; ++r) {
        const float* row = feat + ((size_t)r * Ww) * Dd + d;
        for (int c = cl; c < ch; ++c) s += row[(size_t)c * Dd];
    }
    float count = (float)((rh - rl) * (ch - cl));
    out[(size_t)n * Dd + d] = s / count;
}

extern "C" void kernel_launch(void* const* d_in, const int* in_sizes, int n_in,
                              void* d_out, int out_size, void* d_ws, size_t ws_size,
                              hipStream_t stream) {
    const float* feat  = (const float*)d_in[0];   // (256,256,256) f32
    const float* boxes = (const float*)d_in[1];   // (2048,4) f32

    const size_t p_bytes = (size_t)Hh * Ww * Dd * sizeof(float);  // 64 MiB

    if (ws_size >= p_bytes) {
        f4* P = (f4*)d_ws;
        k1_rowscan<<<Hh * 4, 256, 0, stream>>>((const f4*)feat, P);
        k2_boxsum<<<NB, 256, 0, stream>>>(P, boxes, (f4*)d_out);
    } else {
        roi_pool_naive<<<NB, 256, 0, stream>>>(feat, boxes, (float*)d_out);
    }
}

// Round 8
// 135.547 us; speedup vs baseline: 1.5542x; 1.1596x over previous
//
#include <hip/hip_runtime.h>

// Problem constants (match reference).
constexpr int Hh = 256;
constexpr int Ww = 256;
constexpr int Dd = 256;
constexpr int NB = 2048;

typedef float f4 __attribute__((ext_vector_type(4)));

// ---------------------------------------------------------------------------
// K1: row-prefix along w:  P[h][w][d] = sum_{w'<=w} feat[h][w'][d].
// Grid = 256 rows x 4 d-quarters = 1024 blocks of 256 thr.
// Block: 16 w-chunks x 16 f4-lanes (64-ch quarter); 16 scan elems/thread in
// registers; chunk totals scanned via LDS. Contiguous accesses throughout.
// ---------------------------------------------------------------------------
__global__ void __launch_bounds__(256) k1_rowscan(const f4* __restrict__ feat,
                                                  f4* __restrict__ P) {
    const int tid = threadIdx.x;
    const int dl  = tid & 15;            // f4 lane within quarter
    const int ck  = tid >> 4;            // w-chunk in [0,16)
    const int h   = blockIdx.x >> 2;
    const int q   = blockIdx.x & 3;      // d-quarter

    __shared__ f4 cs[16][16];

    const size_t base = ((size_t)h * Ww + ck * 16) * 64 + q * 16 + dl;
    f4 v[16];
#pragma unroll
    for (int j = 0; j < 16; ++j)
        v[j] = __builtin_nontemporal_load(feat + base + (size_t)j * 64);
#pragma unroll
    for (int j = 1; j < 16; ++j) v[j] += v[j - 1];

    cs[ck][dl] = v[15];
    __syncthreads();
    f4 off = {0.f, 0.f, 0.f, 0.f};
    for (int k = 0; k < ck; ++k) off += cs[k][dl];   // ck wave-uniform

#pragma unroll
    for (int j = 0; j < 16; ++j) P[base + (size_t)j * 64] = v[j] + off;
}

// ---------------------------------------------------------------------------
// K2: block = (column c, d-quarter q). Reads its P-column ONCE (64 KiB),
// column-scans it (registers + LDS chunk totals), stages the SAT column S in
// LDS, then serves every box with ch-1==c (+1) or cl-1==c (-1):
//   out[n][q] += sgn * (S[rh-1] - S[rl-1]) / count
// <=2 commutative atomic adds per out element -> deterministic. P is read
// exactly once grid-wide (64 MiB vs R7's 350 MB box-gather).
// Bounds math replicates f32 JAX semantics exactly:
//   lo = max(0, floor(lo_f*size));  hi = rint(hi_f*size + 0.5)  (ties-even)
//   hi = min(size, max(lo+1, hi))
// ---------------------------------------------------------------------------
__global__ void __launch_bounds__(256) k2_colserve(const f4* __restrict__ P,
                                                   const float* __restrict__ boxes,
                                                   float* __restrict__ out) {
    extern __shared__ f4 lds[];
    f4*  S      = lds;                    // [256][17] padded rows
    f4*  cs     = lds + 256 * 17;         // [16][16]
    int* mlist  = (int*)(lds + 256 * 17 + 256);  // [256]
    int* mcount = mlist + 256;

    const int tid = threadIdx.x;
    const int f   = tid & 15;            // f4 lane within quarter
    const int hc  = tid >> 4;            // h-chunk in [0,16)
    const int c   = blockIdx.x >> 2;     // column
    const int q   = blockIdx.x & 3;      // d-quarter

    // Column load: P[hc*16+j][c][q*16+f]; wave = 4 h-rows x 256B granules.
    const size_t colbase = ((size_t)(hc * 16) * Ww + c) * 64 + q * 16 + f;
    const size_t rstride = (size_t)Ww * 64;
    f4 v[16];
#pragma unroll
    for (int j = 0; j < 16; ++j) v[j] = P[colbase + (size_t)j * rstride];
#pragma unroll
    for (int j = 1; j < 16; ++j) v[j] += v[j - 1];

    cs[hc * 16 + f] = v[15];
    __syncthreads();
    f4 off = {0.f, 0.f, 0.f, 0.f};
    for (int k = 0; k < hc; ++k) off += cs[k * 16 + f];

#pragma unroll
    for (int j = 0; j < 16; ++j) S[(hc * 16 + j) * 17 + f] = v[j] + off;

    // Serve boxes in batches of 256 (bounded LDS list, overflow-safe).
    for (int batch = 0; batch < NB; batch += 256) {
        __syncthreads();                 // S ready / previous serve done
        if (tid == 0) *mcount = 0;
        __syncthreads();

        {
            const int n = batch + tid;
            float x1 = boxes[n * 4 + 0];
            float x2 = boxes[n * 4 + 2];
            int cl = max(0, (int)floorf(x1 * 256.0f));
            int ch = (int)rintf(x2 * 256.0f + 0.5f);
            ch = min(Ww, max(cl + 1, ch));
            if (ch - 1 == c || cl - 1 == c) {
                int idx = atomicAdd(mcount, 1);
                mlist[idx] = n;
            }
        }
        __syncthreads();

        const int M = *mcount;
        // 4 boxes served concurrently; 64 threads (one wave-half pair) per box.
        const int grp  = tid >> 6;       // [0,4)
        const int lane = tid & 63;       // float index within quarter
        for (int m = grp; m < M; m += 4) {
            const int bn = mlist[m];
            float x1 = boxes[bn * 4 + 0];
            float y1 = boxes[bn * 4 + 1];
            float x2 = boxes[bn * 4 + 2];
            float y2 = boxes[bn * 4 + 3];

            int cl = max(0, (int)floorf(x1 * 256.0f));
            int ch = (int)rintf(x2 * 256.0f + 0.5f);
            ch = min(Ww, max(cl + 1, ch));
            int rl = max(0, (int)floorf(y1 * 256.0f));
            int rh = (int)rintf(y2 * 256.0f + 0.5f);
            rh = min(Hh, max(rl + 1, rh));

            float sgn = (ch - 1 == c) ? 1.0f : -1.0f;
            float scale = sgn / (float)((rh - rl) * (ch - cl));

            const float* Sf = (const float*)S;
            float hi = Sf[(rh - 1) * 68 + lane];
            float lo = (rl > 0) ? Sf[(rl - 1) * 68 + lane] : 0.0f;
            atomicAdd(out + (size_t)bn * Dd + q * 64 + lane, (hi - lo) * scale);
        }
    }
}

// ---------------------------------------------------------------------------
// Fallback (ws too small for the 64 MiB prefix buffer): direct summation.
// ---------------------------------------------------------------------------
__global__ void __launch_bounds__(256) roi_pool_naive(const float* __restrict__ feat,
                                                      const float* __restrict__ boxes,
                                                      float* __restrict__ out) {
    int n = blockIdx.x;
    int d = threadIdx.x;

    float x1 = boxes[n * 4 + 0];
    float y1 = boxes[n * 4 + 1];
    float x2 = boxes[n * 4 + 2];
    float y2 = boxes[n * 4 + 3];

    int cl = max(0, (int)floorf(x1 * 256.0f));
    int ch = (int)rintf(x2 * 256.0f + 0.5f);
    ch = min(Ww, max(cl + 1, ch));
    int rl = max(0, (int)floorf(y1 * 256.0f));
    int rh = (int)rintf(y2 * 256.0f + 0.5f);
    rh = min(Hh, max(rl + 1, rh));

    float s = 0.0f;
    for (int r = rl; r < rh; ++r) {
        const float* row = feat + ((size_t)r * Ww) * Dd + d;
        for (int c2 = cl; c2 < ch; ++c2) s += row[(size_t)c2 * Dd];
    }
    float count = (float)((rh - rl) * (ch - cl));
    out[(size_t)n * Dd + d] = s / count;
}

extern "C" void kernel_launch(void* const* d_in, const int* in_sizes, int n_in,
                              void* d_out, int out_size, void* d_ws, size_t ws_size,
                              hipStream_t stream) {
    const float* feat  = (const float*)d_in[0];   // (256,256,256) f32
    const float* boxes = (const float*)d_in[1];   // (2048,4) f32

    const size_t p_bytes   = (size_t)Hh * Ww * Dd * sizeof(float);      // 64 MiB
    const size_t lds_bytes = (256 * 17 + 256) * sizeof(f4) + 257 * 4;   // ~74.8 KiB

    if (ws_size >= p_bytes) {
        f4* P = (f4*)d_ws;
        // out receives only atomic adds -> zero it every call.
        hipMemsetAsync(d_out, 0, (size_t)NB * Dd * sizeof(float), stream);
        k1_rowscan<<<Hh * 4, 256, 0, stream>>>((const f4*)feat, P);
        hipFuncSetAttribute((const void*)k2_colserve,
                            hipFuncAttributeMaxDynamicSharedMemorySize,
                            (int)lds_bytes);
        k2_colserve<<<Ww * 4, 256, lds_bytes, stream>>>(P, boxes, (float*)d_out);
    } else {
        roi_pool_naive<<<NB, 256, 0, stream>>>(feat, boxes, (float*)d_out);
    }
}